// Round 1
// baseline (466.719 us; speedup 1.0000x reference)
//
#include <hip/hip_runtime.h>
#include <hip/hip_bf16.h>

#define NN 50000
#define NE 600000
#define DD 128
#define RR 8
#define KA 1152   /* R*D + D : 8 relations + root appended as 9th */

typedef __attribute__((ext_vector_type(8))) short short8;
typedef __attribute__((ext_vector_type(4))) float f32x4;

__device__ __forceinline__ unsigned short f2b(float x){
  __hip_bfloat16 h = __float2bfloat16(x);
  return __builtin_bit_cast(unsigned short, h);
}
__device__ __forceinline__ float blo(unsigned u){ return __builtin_bit_cast(float, u << 16); }
__device__ __forceinline__ float bhi(unsigned u){ return __builtin_bit_cast(float, u & 0xFFFF0000u); }
__device__ __forceinline__ unsigned pack2(float a, float b){
  return (unsigned)f2b(a) | ((unsigned)f2b(b) << 16);
}

#define GLDS16(g, l) __builtin_amdgcn_global_load_lds( \
    (const __attribute__((address_space(1))) void*)(g), \
    (__attribute__((address_space(3))) void*)(l), 16, 0, 0)

// ---------------- edge structure build ----------------
__global__ __launch_bounds__(256) void k_hist(const int* __restrict__ ei,
                                              const int* __restrict__ et,
                                              int* __restrict__ deg,
                                              int* __restrict__ cnt_vr) {
  int e = blockIdx.x * 256 + threadIdx.x;
  if (e < NE) {
    int dst = ei[NE + e];
    int r = et[e];
    atomicAdd(&deg[dst], 1);
    atomicAdd(&cnt_vr[dst * RR + r], 1);
  }
}

__global__ __launch_bounds__(1024) void k_scan(const int* __restrict__ deg,
                                               int* __restrict__ rowptr,
                                               int* __restrict__ cur) {
  __shared__ int buf[1024];
  __shared__ int carry;
  int t = threadIdx.x;
  if (t == 0) { carry = 0; rowptr[0] = 0; }
  __syncthreads();
  for (int base = 0; base < NN; base += 1024) {
    int i = base + t;
    int v = (i < NN) ? deg[i] : 0;
    buf[t] = v;
    __syncthreads();
    #pragma unroll
    for (int off = 1; off < 1024; off <<= 1) {
      int add = (t >= off) ? buf[t - off] : 0;
      __syncthreads();
      buf[t] += add;
      __syncthreads();
    }
    int inc = buf[t] + carry;          // inclusive prefix including prior chunks
    if (i < NN) { rowptr[i + 1] = inc; cur[i] = inc - v; }
    __syncthreads();
    if (t == 1023) carry = inc;
    __syncthreads();
  }
}

__global__ __launch_bounds__(256) void k_scatter(const int* __restrict__ ei,
                                                 const int* __restrict__ et,
                                                 int* __restrict__ cur,
                                                 unsigned* __restrict__ packed) {
  int e = blockIdx.x * 256 + threadIdx.x;
  if (e < NE) {
    int src = ei[e];
    int dst = ei[NE + e];
    int r = et[e];
    int p = atomicAdd(&cur[dst], 1);
    packed[p] = (unsigned)src | ((unsigned)r << 16);   // src < 65536 OK
  }
}

// ---------------- prep: bf16 conversions ----------------
__global__ __launch_bounds__(256) void k_xb(const float* __restrict__ x,
                                            unsigned* __restrict__ xb2) {
  int i = blockIdx.x * 256 + threadIdx.x;   // index of float2
  if (i < NN * (DD / 2)) {
    float2 v = ((const float2*)x)[i];
    xb2[i] = pack2(v.x, v.y);
  }
}

// WT[l][n][k] bf16, k in [0,1152): k<1024 -> rel_w[l][k][n], else root_w[l][k-1024][n]
__global__ __launch_bounds__(256) void k_wt(const float* __restrict__ rel_w,
                                            const float* __restrict__ root_w,
                                            unsigned short* __restrict__ WT) {
  int idx = blockIdx.x * 256 + threadIdx.x;
  if (idx >= 2 * DD * KA) return;
  int k = idx % KA;
  int n = (idx / KA) % DD;
  int l = idx / (KA * DD);
  float v;
  if (k < RR * DD) v = rel_w[((size_t)l * RR * DD + k) * DD + n];
  else             v = root_w[((size_t)l * DD + (k - RR * DD)) * DD + n];
  WT[idx] = f2b(v);
}

// PT[n][k] = proj_w[k][n], k<256
__global__ __launch_bounds__(256) void k_pt(const float* __restrict__ proj_w,
                                            unsigned short* __restrict__ PT) {
  int idx = blockIdx.x * 256 + threadIdx.x;
  if (idx >= DD * 256) return;
  int k = idx % 256;
  int n = idx / 256;
  PT[idx] = f2b(proj_w[(size_t)k * DD + n]);
}

// ---------------- aggregation: one wave per node ----------------
__global__ __launch_bounds__(256) void k_agg(const unsigned short* __restrict__ xb, int xstride,
                                             const unsigned* __restrict__ packed,
                                             const int* __restrict__ rowptr,
                                             const int* __restrict__ cnt_vr,
                                             unsigned short* __restrict__ A2) {
  int v = blockIdx.x * 4 + (threadIdx.x >> 6);
  int l = threadIdx.x & 63;
  if (v >= NN) return;
  float acc[RR][2];
  #pragma unroll
  for (int r = 0; r < RR; r++) { acc[r][0] = 0.f; acc[r][1] = 0.f; }
  int e0 = rowptr[v], e1 = rowptr[v + 1];
  for (int e = e0; e < e1; e++) {
    unsigned p = packed[e];
    int src = p & 0xFFFF;
    int r = p >> 16;
    unsigned x2 = *(const unsigned*)(xb + (size_t)src * xstride + 2 * l);
    float x0 = blo(x2), x1 = bhi(x2);
    #pragma unroll
    for (int rr = 0; rr < RR; rr++) {
      acc[rr][0] += (r == rr) ? x0 : 0.f;
      acc[rr][1] += (r == rr) ? x1 : 0.f;
    }
  }
  unsigned short* row = A2 + (size_t)v * KA;
  #pragma unroll
  for (int rr = 0; rr < RR; rr++) {
    int c = cnt_vr[v * RR + rr];
    float s = (c > 0) ? (1.0f / (float)c) : 1.0f;
    ((unsigned*)row)[rr * 64 + l] = pack2(acc[rr][0] * s, acc[rr][1] * s);
  }
  // root chunk: own features (cols 1024..1152)
  unsigned xs = *(const unsigned*)(xb + (size_t)v * xstride + 2 * l);
  ((unsigned*)(row + RR * DD))[l] = xs;
}

// ---------------- bf16 MFMA GEMM: C[M,128] = act(A[M,K] * BT[128,K]^T + bias) ----------------
__global__ __launch_bounds__(256) void k_gemm(const unsigned short* __restrict__ A, int lda,
                                              const unsigned short* __restrict__ BT, int ldb,
                                              int M, int K,
                                              const float* __restrict__ bias,
                                              float* __restrict__ outf,
                                              unsigned short* __restrict__ hb, int hboff,
                                              int dorelu) {
  __shared__ unsigned short sA[128 * 64];   // [row][chunk^ (row&7)][8] bf16
  __shared__ unsigned short sB[128 * 64];
  int t = threadIdx.x;
  int bm = blockIdx.x;
  int lane = t & 63, wv = t >> 6;
  int wm = wv >> 1, wn = wv & 1;
  int l15 = lane & 15, lk = lane >> 4;

  f32x4 acc[4][4];
  #pragma unroll
  for (int mi = 0; mi < 4; mi++)
    #pragma unroll
    for (int ni = 0; ni < 4; ni++)
      acc[mi][ni] = (f32x4){0.f, 0.f, 0.f, 0.f};

  int nkt = K >> 6;
  for (int kt = 0; kt < nkt; kt++) {
    // stage A tile [128 rows][64 cols bf16] with source-side XOR swizzle
    #pragma unroll
    for (int i = 0; i < 4; i++) {
      int f = i * 256 + t;
      int row = f >> 3, cl = f & 7;
      int cg = cl ^ (row & 7);
      int rg = bm * 128 + row;
      if (rg >= M) rg = M - 1;
      const unsigned short* src = A + (size_t)rg * lda + kt * 64 + cg * 8;
      GLDS16(src, &sA[f * 8]);
    }
    // stage B tile (BT rows are output columns; 128 exact)
    #pragma unroll
    for (int i = 0; i < 4; i++) {
      int f = i * 256 + t;
      int row = f >> 3, cl = f & 7;
      int cg = cl ^ (row & 7);
      const unsigned short* src = BT + (size_t)row * ldb + kt * 64 + cg * 8;
      GLDS16(src, &sB[f * 8]);
    }
    __syncthreads();

    short8 af[4][2], bf[4][2];
    #pragma unroll
    for (int mi = 0; mi < 4; mi++) {
      #pragma unroll
      for (int kk = 0; kk < 2; kk++) {
        int r = wm * 64 + mi * 16 + l15;
        int c = kk * 4 + lk;
        af[mi][kk] = *(const short8*)&sA[((r << 3) + (c ^ (r & 7))) << 3];
        int rb = wn * 64 + mi * 16 + l15;
        bf[mi][kk] = *(const short8*)&sB[((rb << 3) + (c ^ (rb & 7))) << 3];
      }
    }
    #pragma unroll
    for (int mi = 0; mi < 4; mi++)
      #pragma unroll
      for (int ni = 0; ni < 4; ni++)
        #pragma unroll
        for (int kk = 0; kk < 2; kk++)
          acc[mi][ni] = __builtin_amdgcn_mfma_f32_16x16x32_bf16(af[mi][kk], bf[ni][kk], acc[mi][ni], 0, 0, 0);
    __syncthreads();
  }

  // epilogue: C row=(lane>>4)*4+j, col=lane&15 within each 16x16 fragment
  #pragma unroll
  for (int mi = 0; mi < 4; mi++) {
    #pragma unroll
    for (int ni = 0; ni < 4; ni++) {
      int cg = wn * 64 + ni * 16 + l15;
      float bv = bias[cg];
      #pragma unroll
      for (int j = 0; j < 4; j++) {
        int rg = bm * 128 + wm * 64 + mi * 16 + lk * 4 + j;
        if (rg < M) {
          float val = acc[mi][ni][j] + bv;
          if (dorelu) val = fmaxf(val, 0.f);
          outf[(size_t)rg * 128 + cg] = val;
          if (hb) hb[(size_t)rg * 256 + hboff + cg] = f2b(val);
        }
      }
    }
  }
}

// ---------------- launch ----------------
extern "C" void kernel_launch(void* const* d_in, const int* in_sizes, int n_in,
                              void* d_out, int out_size, void* d_ws, size_t ws_size,
                              hipStream_t stream) {
  const float* node_feat = (const float*)d_in[0];
  const int*   ei        = (const int*)d_in[1];
  const int*   et        = (const int*)d_in[2];
  const float* rel_w     = (const float*)d_in[3];
  const float* root_w    = (const float*)d_in[4];
  const float* bias      = (const float*)d_in[5];
  const float* proj_w    = (const float*)d_in[6];
  const float* proj_b    = (const float*)d_in[7];
  float* out = (float*)d_out;

  // workspace carve (bytes, 256-aligned)
  char* ws = (char*)d_ws;
  size_t off = 0;
  auto carve = [&](size_t bytes) { void* p = ws + off; off = (off + bytes + 255) & ~(size_t)255; return p; };
  unsigned short* A2   = (unsigned short*)carve((size_t)NN * KA * 2);      // 115.2 MB
  unsigned short* Hb   = (unsigned short*)carve((size_t)NN * 256 * 2);     // 25.6 MB  [h1|h2] bf16
  unsigned short* xb   = (unsigned short*)carve((size_t)NN * DD * 2);      // 12.8 MB
  unsigned short* WT   = (unsigned short*)carve((size_t)2 * DD * KA * 2);  // 0.59 MB
  unsigned short* PT   = (unsigned short*)carve((size_t)DD * 256 * 2);     // 64 KB
  int* cnt_vr          = (int*)carve((size_t)NN * RR * 4);                 // 1.6 MB
  int* deg             = (int*)carve((size_t)NN * 4);
  int* rowptr          = (int*)carve((size_t)(NN + 1) * 4);
  int* cur             = (int*)carve((size_t)NN * 4);
  unsigned* packed     = (unsigned*)carve((size_t)NE * 4);                 // 2.4 MB
  (void)ws_size; (void)in_sizes; (void)n_in; (void)out_size;

  hipMemsetAsync(cnt_vr, 0, (size_t)NN * RR * 4, stream);
  hipMemsetAsync(deg, 0, (size_t)NN * 4, stream);

  int egrid = (NE + 255) / 256;
  k_hist<<<egrid, 256, 0, stream>>>(ei, et, deg, cnt_vr);
  k_scan<<<1, 1024, 0, stream>>>(deg, rowptr, cur);
  k_scatter<<<egrid, 256, 0, stream>>>(ei, et, cur, packed);

  k_xb<<<(NN * (DD / 2) + 255) / 256, 256, 0, stream>>>(node_feat, (unsigned*)xb);
  k_wt<<<(2 * DD * KA + 255) / 256, 256, 0, stream>>>(rel_w, root_w, WT);
  k_pt<<<(DD * 256 + 255) / 256, 256, 0, stream>>>(proj_w, PT);

  int mgrid = (NN + 127) / 128;   // 391

  // layer 1: agg from node_feat(bf16), GEMM -> h1 (fp32 to d_out, bf16 to Hb cols 0..128)
  k_agg<<<NN / 4, 256, 0, stream>>>(xb, DD, packed, rowptr, cnt_vr, A2);
  k_gemm<<<mgrid, 256, 0, stream>>>(A2, KA, WT, KA, NN, KA, bias,
                                    out + (size_t)NN * DD, Hb, 0, 1);

  // layer 2: agg from h1 (bf16, stride 256 in Hb), GEMM -> h2
  k_agg<<<NN / 4, 256, 0, stream>>>(Hb, 256, packed, rowptr, cnt_vr, A2);
  k_gemm<<<mgrid, 256, 0, stream>>>(A2, KA, WT + (size_t)DD * KA, KA, NN, KA, bias + DD,
                                    out + (size_t)2 * NN * DD, Hb, DD, 1);

  // projection: final = [h1|h2] @ proj_w + proj_b (no relu)
  k_gemm<<<mgrid, 256, 0, stream>>>(Hb, 256, PT, 256, NN, 256, proj_b,
                                    out, (unsigned short*)nullptr, 0, 0);
}

// Round 2
// 382.435 us; speedup vs baseline: 1.2204x; 1.2204x over previous
//
#include <hip/hip_runtime.h>
#include <hip/hip_bf16.h>

#define NN 50000
#define NE 600000
#define DD 128
#define RR 8
#define KA 1152   /* R*D + D : 8 relations + root appended as 9th */

#define SCHUNK 1024
#define NBSCAN ((NN + SCHUNK - 1) / SCHUNK)   /* 49 */

typedef __attribute__((ext_vector_type(8))) short short8;
typedef __attribute__((ext_vector_type(4))) float f32x4;

__device__ __forceinline__ unsigned short f2b(float x){
  __hip_bfloat16 h = __float2bfloat16(x);
  return __builtin_bit_cast(unsigned short, h);
}
__device__ __forceinline__ float blo(unsigned u){ return __builtin_bit_cast(float, u << 16); }
__device__ __forceinline__ float bhi(unsigned u){ return __builtin_bit_cast(float, u & 0xFFFF0000u); }
__device__ __forceinline__ unsigned pack2(float a, float b){
  return (unsigned)f2b(a) | ((unsigned)f2b(b) << 16);
}

#define GLDS16(g, l) __builtin_amdgcn_global_load_lds( \
    (const __attribute__((address_space(1))) void*)(g), \
    (__attribute__((address_space(3))) void*)(l), 16, 0, 0)

// ---------------- edge structure build ----------------
__global__ __launch_bounds__(256) void k_hist(const int* __restrict__ ei,
                                              const int* __restrict__ et,
                                              int* __restrict__ deg,
                                              int* __restrict__ cnt_vr) {
  int e = blockIdx.x * 256 + threadIdx.x;
  if (e < NE) {
    int dst = ei[NE + e];
    int r = et[e];
    atomicAdd(&deg[dst], 1);
    atomicAdd(&cnt_vr[dst * RR + r], 1);
  }
}

// hierarchical scan, step 1: per-block sums (1024 elems / block)
__global__ __launch_bounds__(256) void k_scan1(const int* __restrict__ deg,
                                               int* __restrict__ bsum) {
  int b = blockIdx.x, t = threadIdx.x;
  int base = b * SCHUNK + t * 4;
  int s = 0;
  if (base + 3 < NN) {
    int4 v = *(const int4*)&deg[base];
    s = v.x + v.y + v.z + v.w;
  } else {
    for (int j = 0; j < 4; j++) if (base + j < NN) s += deg[base + j];
  }
  #pragma unroll
  for (int off = 32; off; off >>= 1) s += __shfl_down(s, off);
  __shared__ int wsum[4];
  int lane = t & 63, wv = t >> 6;
  if (lane == 0) wsum[wv] = s;
  __syncthreads();
  if (t == 0) bsum[b] = wsum[0] + wsum[1] + wsum[2] + wsum[3];
}

// step 2: exclusive scan of the 49 block sums (one wave)
__global__ __launch_bounds__(64) void k_scan2(const int* __restrict__ bsum,
                                              int* __restrict__ boff) {
  int l = threadIdx.x;
  int v = (l < NBSCAN) ? bsum[l] : 0;
  int x = v;
  #pragma unroll
  for (int off = 1; off < 64; off <<= 1) {
    int y = __shfl_up(x, off);
    if (l >= off) x += y;
  }
  if (l < NBSCAN) boff[l] = x - v;
}

// step 3: intra-block scan + block offset -> rowptr / cur
__global__ __launch_bounds__(256) void k_scan3(const int* __restrict__ deg,
                                               const int* __restrict__ boff,
                                               int* __restrict__ rowptr,
                                               int* __restrict__ cur) {
  int b = blockIdx.x, t = threadIdx.x;
  int lane = t & 63, wv = t >> 6;
  int base = b * SCHUNK + t * 4;
  int v[4]; int s = 0;
  #pragma unroll
  for (int j = 0; j < 4; j++) { v[j] = (base + j < NN) ? deg[base + j] : 0; s += v[j]; }
  int x = s;
  #pragma unroll
  for (int off = 1; off < 64; off <<= 1) {
    int y = __shfl_up(x, off);
    if (lane >= off) x += y;
  }
  __shared__ int wtot[4];
  if (lane == 63) wtot[wv] = x;
  __syncthreads();
  int woff = 0;
  for (int w = 0; w < wv; w++) woff += wtot[w];
  int exc = boff[b] + woff + x - s;
  #pragma unroll
  for (int j = 0; j < 4; j++) {
    if (base + j < NN) { cur[base + j] = exc; rowptr[base + j + 1] = exc + v[j]; }
    exc += v[j];
  }
  if (b == 0 && t == 0) rowptr[0] = 0;
}

__global__ __launch_bounds__(256) void k_scatter(const int* __restrict__ ei,
                                                 const int* __restrict__ et,
                                                 int* __restrict__ cur,
                                                 unsigned* __restrict__ packed) {
  int e = blockIdx.x * 256 + threadIdx.x;
  if (e < NE) {
    int src = ei[e];
    int dst = ei[NE + e];
    int r = et[e];
    int p = atomicAdd(&cur[dst], 1);
    packed[p] = (unsigned)src | ((unsigned)r << 16);   // src < 65536 OK
  }
}

// ---------------- prep: bf16 conversions ----------------
__global__ __launch_bounds__(256) void k_xb(const float* __restrict__ x,
                                            unsigned* __restrict__ xb2) {
  int i = blockIdx.x * 256 + threadIdx.x;   // index of float2
  if (i < NN * (DD / 2)) {
    float2 v = ((const float2*)x)[i];
    xb2[i] = pack2(v.x, v.y);
  }
}

// WT[l][n][k] bf16, k in [0,1152): k<1024 -> rel_w[l][k][n], else root_w[l][k-1024][n]
__global__ __launch_bounds__(256) void k_wt(const float* __restrict__ rel_w,
                                            const float* __restrict__ root_w,
                                            unsigned short* __restrict__ WT) {
  int idx = blockIdx.x * 256 + threadIdx.x;
  if (idx >= 2 * DD * KA) return;
  int k = idx % KA;
  int n = (idx / KA) % DD;
  int l = idx / (KA * DD);
  float v;
  if (k < RR * DD) v = rel_w[((size_t)l * RR * DD + k) * DD + n];
  else             v = root_w[((size_t)l * DD + (k - RR * DD)) * DD + n];
  WT[idx] = f2b(v);
}

// PT[n][k] = proj_w[k][n], k<256
__global__ __launch_bounds__(256) void k_pt(const float* __restrict__ proj_w,
                                            unsigned short* __restrict__ PT) {
  int idx = blockIdx.x * 256 + threadIdx.x;
  if (idx >= DD * 256) return;
  int k = idx % 256;
  int n = idx / 256;
  PT[idx] = f2b(proj_w[(size_t)k * DD + n]);
}

// ---------------- aggregation: one wave per node ----------------
__global__ __launch_bounds__(256) void k_agg(const unsigned short* __restrict__ xb, int xstride,
                                             const unsigned* __restrict__ packed,
                                             const int* __restrict__ rowptr,
                                             const int* __restrict__ cnt_vr,
                                             unsigned short* __restrict__ A2) {
  int v = blockIdx.x * 4 + (threadIdx.x >> 6);
  int l = threadIdx.x & 63;
  if (v >= NN) return;
  float acc[RR][2];
  #pragma unroll
  for (int r = 0; r < RR; r++) { acc[r][0] = 0.f; acc[r][1] = 0.f; }
  int e0 = rowptr[v], e1 = rowptr[v + 1];
  for (int e = e0; e < e1; e++) {
    unsigned p = packed[e];
    int src = p & 0xFFFF;
    int r = p >> 16;
    unsigned x2 = *(const unsigned*)(xb + (size_t)src * xstride + 2 * l);
    float x0 = blo(x2), x1 = bhi(x2);
    #pragma unroll
    for (int rr = 0; rr < RR; rr++) {
      acc[rr][0] += (r == rr) ? x0 : 0.f;
      acc[rr][1] += (r == rr) ? x1 : 0.f;
    }
  }
  unsigned short* row = A2 + (size_t)v * KA;
  #pragma unroll
  for (int rr = 0; rr < RR; rr++) {
    int c = cnt_vr[v * RR + rr];
    float s = (c > 0) ? (1.0f / (float)c) : 1.0f;
    ((unsigned*)row)[rr * 64 + l] = pack2(acc[rr][0] * s, acc[rr][1] * s);
  }
  // root chunk: own features (cols 1024..1152)
  unsigned xs = *(const unsigned*)(xb + (size_t)v * xstride + 2 * l);
  ((unsigned*)(row + RR * DD))[l] = xs;
}

// ---------------- bf16 MFMA GEMM: C[M,128] = act(A[M,K] * BT[128,K]^T + bias) ----------------
__global__ __launch_bounds__(256) void k_gemm(const unsigned short* __restrict__ A, int lda,
                                              const unsigned short* __restrict__ BT, int ldb,
                                              int M, int K,
                                              const float* __restrict__ bias,
                                              float* __restrict__ outf,
                                              unsigned short* __restrict__ hb, int hboff,
                                              int dorelu) {
  __shared__ unsigned short sA[128 * 64];   // [row][chunk^ (row&7)][8] bf16
  __shared__ unsigned short sB[128 * 64];
  int t = threadIdx.x;
  int bm = blockIdx.x;
  int lane = t & 63, wv = t >> 6;
  int wm = wv >> 1, wn = wv & 1;
  int l15 = lane & 15, lk = lane >> 4;

  f32x4 acc[4][4];
  #pragma unroll
  for (int mi = 0; mi < 4; mi++)
    #pragma unroll
    for (int ni = 0; ni < 4; ni++)
      acc[mi][ni] = (f32x4){0.f, 0.f, 0.f, 0.f};

  int nkt = K >> 6;
  for (int kt = 0; kt < nkt; kt++) {
    // stage A tile [128 rows][64 cols bf16] with source-side XOR swizzle
    #pragma unroll
    for (int i = 0; i < 4; i++) {
      int f = i * 256 + t;
      int row = f >> 3, cl = f & 7;
      int cg = cl ^ (row & 7);
      int rg = bm * 128 + row;
      if (rg >= M) rg = M - 1;
      const unsigned short* src = A + (size_t)rg * lda + kt * 64 + cg * 8;
      GLDS16(src, &sA[f * 8]);
    }
    // stage B tile (BT rows are output columns; 128 exact)
    #pragma unroll
    for (int i = 0; i < 4; i++) {
      int f = i * 256 + t;
      int row = f >> 3, cl = f & 7;
      int cg = cl ^ (row & 7);
      const unsigned short* src = BT + (size_t)row * ldb + kt * 64 + cg * 8;
      GLDS16(src, &sB[f * 8]);
    }
    __syncthreads();

    short8 af[4][2], bf[4][2];
    #pragma unroll
    for (int mi = 0; mi < 4; mi++) {
      #pragma unroll
      for (int kk = 0; kk < 2; kk++) {
        int r = wm * 64 + mi * 16 + l15;
        int c = kk * 4 + lk;
        af[mi][kk] = *(const short8*)&sA[((r << 3) + (c ^ (r & 7))) << 3];
        int rb = wn * 64 + mi * 16 + l15;
        bf[mi][kk] = *(const short8*)&sB[((rb << 3) + (c ^ (rb & 7))) << 3];
      }
    }
    #pragma unroll
    for (int mi = 0; mi < 4; mi++)
      #pragma unroll
      for (int ni = 0; ni < 4; ni++)
        #pragma unroll
        for (int kk = 0; kk < 2; kk++)
          acc[mi][ni] = __builtin_amdgcn_mfma_f32_16x16x32_bf16(af[mi][kk], bf[ni][kk], acc[mi][ni], 0, 0, 0);
    __syncthreads();
  }

  // epilogue: C row=(lane>>4)*4+j, col=lane&15 within each 16x16 fragment
  #pragma unroll
  for (int mi = 0; mi < 4; mi++) {
    #pragma unroll
    for (int ni = 0; ni < 4; ni++) {
      int cg = wn * 64 + ni * 16 + l15;
      float bv = bias[cg];
      #pragma unroll
      for (int j = 0; j < 4; j++) {
        int rg = bm * 128 + wm * 64 + mi * 16 + lk * 4 + j;
        if (rg < M) {
          float val = acc[mi][ni][j] + bv;
          if (dorelu) val = fmaxf(val, 0.f);
          outf[(size_t)rg * 128 + cg] = val;
          if (hb) hb[(size_t)rg * 256 + hboff + cg] = f2b(val);
        }
      }
    }
  }
}

// ---------------- launch ----------------
extern "C" void kernel_launch(void* const* d_in, const int* in_sizes, int n_in,
                              void* d_out, int out_size, void* d_ws, size_t ws_size,
                              hipStream_t stream) {
  const float* node_feat = (const float*)d_in[0];
  const int*   ei        = (const int*)d_in[1];
  const int*   et        = (const int*)d_in[2];
  const float* rel_w     = (const float*)d_in[3];
  const float* root_w    = (const float*)d_in[4];
  const float* bias      = (const float*)d_in[5];
  const float* proj_w    = (const float*)d_in[6];
  const float* proj_b    = (const float*)d_in[7];
  float* out = (float*)d_out;

  // workspace carve (bytes, 256-aligned)
  char* ws = (char*)d_ws;
  size_t off = 0;
  auto carve = [&](size_t bytes) { void* p = ws + off; off = (off + bytes + 255) & ~(size_t)255; return p; };
  unsigned short* A2   = (unsigned short*)carve((size_t)NN * KA * 2);      // 115.2 MB
  unsigned short* Hb   = (unsigned short*)carve((size_t)NN * 256 * 2);     // 25.6 MB  [h1|h2] bf16
  unsigned short* xb   = (unsigned short*)carve((size_t)NN * DD * 2);      // 12.8 MB
  unsigned short* WT   = (unsigned short*)carve((size_t)2 * DD * KA * 2);  // 0.59 MB
  unsigned short* PT   = (unsigned short*)carve((size_t)DD * 256 * 2);     // 64 KB
  int* cnt_vr          = (int*)carve((size_t)NN * RR * 4);                 // 1.6 MB
  int* deg             = (int*)carve((size_t)NN * 4);
  int* rowptr          = (int*)carve((size_t)(NN + 1) * 4);
  int* cur             = (int*)carve((size_t)NN * 4);
  unsigned* packed     = (unsigned*)carve((size_t)NE * 4);                 // 2.4 MB
  int* bsum            = (int*)carve((size_t)64 * 4);
  int* boff            = (int*)carve((size_t)64 * 4);
  (void)ws_size; (void)in_sizes; (void)n_in; (void)out_size;

  hipMemsetAsync(cnt_vr, 0, (size_t)NN * RR * 4, stream);
  hipMemsetAsync(deg, 0, (size_t)NN * 4, stream);

  int egrid = (NE + 255) / 256;
  k_hist<<<egrid, 256, 0, stream>>>(ei, et, deg, cnt_vr);
  k_scan1<<<NBSCAN, 256, 0, stream>>>(deg, bsum);
  k_scan2<<<1, 64, 0, stream>>>(bsum, boff);
  k_scan3<<<NBSCAN, 256, 0, stream>>>(deg, boff, rowptr, cur);
  k_scatter<<<egrid, 256, 0, stream>>>(ei, et, cur, packed);

  k_xb<<<(NN * (DD / 2) + 255) / 256, 256, 0, stream>>>(node_feat, (unsigned*)xb);
  k_wt<<<(2 * DD * KA + 255) / 256, 256, 0, stream>>>(rel_w, root_w, WT);
  k_pt<<<(DD * 256 + 255) / 256, 256, 0, stream>>>(proj_w, PT);

  int mgrid = (NN + 127) / 128;   // 391

  // layer 1: agg from node_feat(bf16), GEMM -> h1 (fp32 to d_out, bf16 to Hb cols 0..128)
  k_agg<<<NN / 4, 256, 0, stream>>>(xb, DD, packed, rowptr, cnt_vr, A2);
  k_gemm<<<mgrid, 256, 0, stream>>>(A2, KA, WT, KA, NN, KA, bias,
                                    out + (size_t)NN * DD, Hb, 0, 1);

  // layer 2: agg from h1 (bf16, stride 256 in Hb), GEMM -> h2
  k_agg<<<NN / 4, 256, 0, stream>>>(Hb, 256, packed, rowptr, cnt_vr, A2);
  k_gemm<<<mgrid, 256, 0, stream>>>(A2, KA, WT + (size_t)DD * KA, KA, NN, KA, bias + DD,
                                    out + (size_t)2 * NN * DD, Hb, DD, 1);

  // projection: final = [h1|h2] @ proj_w + proj_b (no relu)
  k_gemm<<<mgrid, 256, 0, stream>>>(Hb, 256, PT, 256, NN, 256, proj_b,
                                    out, (unsigned short*)nullptr, 0, 0);
}

// Round 3
// 308.882 us; speedup vs baseline: 1.5110x; 1.2381x over previous
//
#include <hip/hip_runtime.h>
#include <hip/hip_bf16.h>

#define NN 50000
#define NE 600000
#define DD 128
#define RR 8
#define KA 1152   /* R*D + D : 8 relations + root appended as 9th */

#define N2 (NN * RR)                       /* 400000 (v,r) segments */
#define SCHUNK 1024
#define NBS2 ((N2 + SCHUNK - 1) / SCHUNK)  /* 391 */

typedef __attribute__((ext_vector_type(8))) short short8;
typedef __attribute__((ext_vector_type(4))) float f32x4;

__device__ __forceinline__ unsigned short f2b(float x){
  __hip_bfloat16 h = __float2bfloat16(x);
  return __builtin_bit_cast(unsigned short, h);
}
__device__ __forceinline__ float blo(unsigned u){ return __builtin_bit_cast(float, u << 16); }
__device__ __forceinline__ float bhi(unsigned u){ return __builtin_bit_cast(float, u & 0xFFFF0000u); }
__device__ __forceinline__ unsigned pack2(float a, float b){
  return (unsigned)f2b(a) | ((unsigned)f2b(b) << 16);
}

#define GLDS16(g, l) __builtin_amdgcn_global_load_lds( \
    (const __attribute__((address_space(1))) void*)(g), \
    (__attribute__((address_space(3))) void*)(l), 16, 0, 0)

// ---------------- edge structure build: CSR over (dst, rel) segments ----------------
__global__ __launch_bounds__(256) void k_hist(const int* __restrict__ ei,
                                              const int* __restrict__ et,
                                              int* __restrict__ cnt_vr) {
  int e = blockIdx.x * 256 + threadIdx.x;
  if (e < NE) {
    int dst = ei[NE + e];
    int r = et[e];
    atomicAdd(&cnt_vr[dst * RR + r], 1);
  }
}

// hierarchical scan over cnt_vr[N2], step 1: per-block sums (1024 elems / block)
__global__ __launch_bounds__(256) void k_scan1(const int* __restrict__ cnt,
                                               int* __restrict__ bsum) {
  int b = blockIdx.x, t = threadIdx.x;
  int base = b * SCHUNK + t * 4;
  int s = 0;
  if (base < N2) {               // N2 % 4 == 0 -> whole int4 in range
    int4 v = *(const int4*)&cnt[base];
    s = v.x + v.y + v.z + v.w;
  }
  #pragma unroll
  for (int off = 32; off; off >>= 1) s += __shfl_down(s, off);
  __shared__ int wsum[4];
  int lane = t & 63, wv = t >> 6;
  if (lane == 0) wsum[wv] = s;
  __syncthreads();
  if (t == 0) bsum[b] = wsum[0] + wsum[1] + wsum[2] + wsum[3];
}

// step 2: exclusive scan of NBS2 (=391) block sums, one block of 512
__global__ __launch_bounds__(512) void k_scan2(const int* __restrict__ bsum,
                                               int* __restrict__ boff) {
  int t = threadIdx.x, lane = t & 63, wv = t >> 6;
  int v = (t < NBS2) ? bsum[t] : 0;
  int x = v;
  #pragma unroll
  for (int off = 1; off < 64; off <<= 1) {
    int y = __shfl_up(x, off);
    if (lane >= off) x += y;
  }
  __shared__ int wt[8];
  if (lane == 63) wt[wv] = x;
  __syncthreads();
  int woff = 0;
  for (int w = 0; w < wv; w++) woff += wt[w];
  if (t < NBS2) boff[t] = woff + x - v;
}

// step 3: intra-block scan + block offset -> rp2 / cur2
__global__ __launch_bounds__(256) void k_scan3(const int* __restrict__ cnt,
                                               const int* __restrict__ boff,
                                               int* __restrict__ rp2,
                                               int* __restrict__ cur2) {
  int b = blockIdx.x, t = threadIdx.x;
  int lane = t & 63, wv = t >> 6;
  int base = b * SCHUNK + t * 4;
  int v[4] = {0, 0, 0, 0};
  int s = 0;
  if (base < N2) {
    int4 q = *(const int4*)&cnt[base];
    v[0] = q.x; v[1] = q.y; v[2] = q.z; v[3] = q.w;
    s = q.x + q.y + q.z + q.w;
  }
  int x = s;
  #pragma unroll
  for (int off = 1; off < 64; off <<= 1) {
    int y = __shfl_up(x, off);
    if (lane >= off) x += y;
  }
  __shared__ int wtot[4];
  if (lane == 63) wtot[wv] = x;
  __syncthreads();
  int woff = 0;
  for (int w = 0; w < wv; w++) woff += wtot[w];
  int exc = boff[b] + woff + x - s;
  if (base < N2) {
    #pragma unroll
    for (int j = 0; j < 4; j++) {
      cur2[base + j] = exc;
      rp2[base + j + 1] = exc + v[j];
      exc += v[j];
    }
  }
  if (b == 0 && t == 0) rp2[0] = 0;
}

__global__ __launch_bounds__(256) void k_scatter(const int* __restrict__ ei,
                                                 const int* __restrict__ et,
                                                 int* __restrict__ cur2,
                                                 unsigned short* __restrict__ psrc) {
  int e = blockIdx.x * 256 + threadIdx.x;
  if (e < NE) {
    int src = ei[e];
    int dst = ei[NE + e];
    int r = et[e];
    int p = atomicAdd(&cur2[dst * RR + r], 1);
    psrc[p] = (unsigned short)src;   // NN < 65536
  }
}

// ---------------- prep: bf16 conversions ----------------
__global__ __launch_bounds__(256) void k_xb(const float* __restrict__ x,
                                            unsigned* __restrict__ xb2) {
  int i = blockIdx.x * 256 + threadIdx.x;   // index of float2
  if (i < NN * (DD / 2)) {
    float2 v = ((const float2*)x)[i];
    xb2[i] = pack2(v.x, v.y);
  }
}

// WT[l][n][k] bf16, k in [0,1152): k<1024 -> rel_w[l][k][n], else root_w[l][k-1024][n]
__global__ __launch_bounds__(256) void k_wt(const float* __restrict__ rel_w,
                                            const float* __restrict__ root_w,
                                            unsigned short* __restrict__ WT) {
  int idx = blockIdx.x * 256 + threadIdx.x;
  if (idx >= 2 * DD * KA) return;
  int k = idx % KA;
  int n = (idx / KA) % DD;
  int l = idx / (KA * DD);
  float v;
  if (k < RR * DD) v = rel_w[((size_t)l * RR * DD + k) * DD + n];
  else             v = root_w[((size_t)l * DD + (k - RR * DD)) * DD + n];
  WT[idx] = f2b(v);
}

// PT[n][k] = proj_w[k][n], k<256
__global__ __launch_bounds__(256) void k_pt(const float* __restrict__ proj_w,
                                            unsigned short* __restrict__ PT) {
  int idx = blockIdx.x * 256 + threadIdx.x;
  if (idx >= DD * 256) return;
  int k = idx % 256;
  int n = idx / 256;
  PT[idx] = f2b(proj_w[(size_t)k * DD + n]);
}

// ---------------- aggregation: one wave per node, (dst,rel)-sorted segments ----------------
__global__ __launch_bounds__(256) void k_agg(const unsigned short* __restrict__ xb, int xstride,
                                             const unsigned short* __restrict__ psrc,
                                             const int* __restrict__ rp2,
                                             unsigned short* __restrict__ A2) {
  int v = blockIdx.x * 4 + (threadIdx.x >> 6);
  int l = threadIdx.x & 63;
  if (v >= NN) return;
  int b = 0;
  if (l < 9) b = rp2[v * RR + l];          // bounds of the 8 segments (9 fenceposts)
  unsigned* row = (unsigned*)(A2 + (size_t)v * KA);
  unsigned xs = *(const unsigned*)(xb + (size_t)v * xstride + 2 * l);
  #pragma unroll
  for (int rr = 0; rr < RR; rr++) {
    int e0 = __shfl(b, rr), e1 = __shfl(b, rr + 1);
    float a0 = 0.f, a1 = 0.f;
    for (int e = e0; e < e1; e++) {
      int src = psrc[e];
      unsigned u = *(const unsigned*)(xb + (size_t)src * xstride + 2 * l);
      a0 += blo(u); a1 += bhi(u);
    }
    float s = (e1 > e0) ? 1.f / (float)(e1 - e0) : 0.f;
    row[rr * 64 + l] = pack2(a0 * s, a1 * s);
  }
  row[RR * 64 + l] = xs;   // root chunk: cols 1024..1152
}

// ---------------- bf16 MFMA GEMM: C[M,128] = act(A[M,K] * BT[128,K]^T + bias) ----------------
__global__ __launch_bounds__(256) void k_gemm(const unsigned short* __restrict__ A, int lda,
                                              const unsigned short* __restrict__ BT, int ldb,
                                              int M, int K,
                                              const float* __restrict__ bias,
                                              float* __restrict__ outf,
                                              unsigned short* __restrict__ hb, int hboff,
                                              int dorelu) {
  __shared__ unsigned short sA[128 * 64];   // [row][chunk^ (row&7)][8] bf16
  __shared__ unsigned short sB[128 * 64];
  int t = threadIdx.x;
  int bm = blockIdx.x;
  int lane = t & 63, wv = t >> 6;
  int wm = wv >> 1, wn = wv & 1;
  int l15 = lane & 15, lk = lane >> 4;

  f32x4 acc[4][4];
  #pragma unroll
  for (int mi = 0; mi < 4; mi++)
    #pragma unroll
    for (int ni = 0; ni < 4; ni++)
      acc[mi][ni] = (f32x4){0.f, 0.f, 0.f, 0.f};

  int nkt = K >> 6;
  for (int kt = 0; kt < nkt; kt++) {
    // stage A tile [128 rows][64 cols bf16] with source-side XOR swizzle
    #pragma unroll
    for (int i = 0; i < 4; i++) {
      int f = i * 256 + t;
      int row = f >> 3, cl = f & 7;
      int cg = cl ^ (row & 7);
      int rg = bm * 128 + row;
      if (rg >= M) rg = M - 1;
      const unsigned short* src = A + (size_t)rg * lda + kt * 64 + cg * 8;
      GLDS16(src, &sA[f * 8]);
    }
    // stage B tile (BT rows are output columns; 128 exact)
    #pragma unroll
    for (int i = 0; i < 4; i++) {
      int f = i * 256 + t;
      int row = f >> 3, cl = f & 7;
      int cg = cl ^ (row & 7);
      const unsigned short* src = BT + (size_t)row * ldb + kt * 64 + cg * 8;
      GLDS16(src, &sB[f * 8]);
    }
    __syncthreads();

    short8 af[4][2], bf[4][2];
    #pragma unroll
    for (int mi = 0; mi < 4; mi++) {
      #pragma unroll
      for (int kk = 0; kk < 2; kk++) {
        int r = wm * 64 + mi * 16 + l15;
        int c = kk * 4 + lk;
        af[mi][kk] = *(const short8*)&sA[((r << 3) + (c ^ (r & 7))) << 3];
        int rb = wn * 64 + mi * 16 + l15;
        bf[mi][kk] = *(const short8*)&sB[((rb << 3) + (c ^ (rb & 7))) << 3];
      }
    }
    #pragma unroll
    for (int mi = 0; mi < 4; mi++)
      #pragma unroll
      for (int ni = 0; ni < 4; ni++)
        #pragma unroll
        for (int kk = 0; kk < 2; kk++)
          acc[mi][ni] = __builtin_amdgcn_mfma_f32_16x16x32_bf16(af[mi][kk], bf[ni][kk], acc[mi][ni], 0, 0, 0);
    __syncthreads();
  }

  // epilogue: C row=(lane>>4)*4+j, col=lane&15 within each 16x16 fragment
  #pragma unroll
  for (int mi = 0; mi < 4; mi++) {
    #pragma unroll
    for (int ni = 0; ni < 4; ni++) {
      int cg = wn * 64 + ni * 16 + l15;
      float bv = bias[cg];
      #pragma unroll
      for (int j = 0; j < 4; j++) {
        int rg = bm * 128 + wm * 64 + mi * 16 + lk * 4 + j;
        if (rg < M) {
          float val = acc[mi][ni][j] + bv;
          if (dorelu) val = fmaxf(val, 0.f);
          outf[(size_t)rg * 128 + cg] = val;
          if (hb) hb[(size_t)rg * 256 + hboff + cg] = f2b(val);
        }
      }
    }
  }
}

// ---------------- launch ----------------
extern "C" void kernel_launch(void* const* d_in, const int* in_sizes, int n_in,
                              void* d_out, int out_size, void* d_ws, size_t ws_size,
                              hipStream_t stream) {
  const float* node_feat = (const float*)d_in[0];
  const int*   ei        = (const int*)d_in[1];
  const int*   et        = (const int*)d_in[2];
  const float* rel_w     = (const float*)d_in[3];
  const float* root_w    = (const float*)d_in[4];
  const float* bias      = (const float*)d_in[5];
  const float* proj_w    = (const float*)d_in[6];
  const float* proj_b    = (const float*)d_in[7];
  float* out = (float*)d_out;

  // workspace carve (bytes, 256-aligned)
  char* ws = (char*)d_ws;
  size_t off = 0;
  auto carve = [&](size_t bytes) { void* p = ws + off; off = (off + bytes + 255) & ~(size_t)255; return p; };
  unsigned short* A2   = (unsigned short*)carve((size_t)NN * KA * 2);      // 115.2 MB
  unsigned short* Hb   = (unsigned short*)carve((size_t)NN * 256 * 2);     // 25.6 MB  [h1|h2] bf16
  unsigned short* xb   = (unsigned short*)carve((size_t)NN * DD * 2);      // 12.8 MB
  unsigned short* WT   = (unsigned short*)carve((size_t)2 * DD * KA * 2);  // 0.59 MB
  unsigned short* PT   = (unsigned short*)carve((size_t)DD * 256 * 2);     // 64 KB
  int* cnt_vr          = (int*)carve((size_t)N2 * 4);                      // 1.6 MB
  int* rp2             = (int*)carve((size_t)(N2 + 1) * 4);                // 1.6 MB
  int* cur2            = (int*)carve((size_t)N2 * 4);                      // 1.6 MB
  unsigned short* psrc = (unsigned short*)carve((size_t)NE * 2);           // 1.2 MB
  int* bsum            = (int*)carve((size_t)512 * 4);
  int* boff            = (int*)carve((size_t)512 * 4);
  (void)ws_size; (void)in_sizes; (void)n_in; (void)out_size;

  hipMemsetAsync(cnt_vr, 0, (size_t)N2 * 4, stream);

  int egrid = (NE + 255) / 256;
  k_hist<<<egrid, 256, 0, stream>>>(ei, et, cnt_vr);
  k_scan1<<<NBS2, 256, 0, stream>>>(cnt_vr, bsum);
  k_scan2<<<1, 512, 0, stream>>>(bsum, boff);
  k_scan3<<<NBS2, 256, 0, stream>>>(cnt_vr, boff, rp2, cur2);
  k_scatter<<<egrid, 256, 0, stream>>>(ei, et, cur2, psrc);

  k_xb<<<(NN * (DD / 2) + 255) / 256, 256, 0, stream>>>(node_feat, (unsigned*)xb);
  k_wt<<<(2 * DD * KA + 255) / 256, 256, 0, stream>>>(rel_w, root_w, WT);
  k_pt<<<(DD * 256 + 255) / 256, 256, 0, stream>>>(proj_w, PT);

  int mgrid = (NN + 127) / 128;   // 391

  // layer 1: agg from node_feat(bf16), GEMM -> h1 (fp32 to d_out, bf16 to Hb cols 0..128)
  k_agg<<<(NN + 3) / 4, 256, 0, stream>>>(xb, DD, psrc, rp2, A2);
  k_gemm<<<mgrid, 256, 0, stream>>>(A2, KA, WT, KA, NN, KA, bias,
                                    out + (size_t)NN * DD, Hb, 0, 1);

  // layer 2: agg from h1 (bf16, stride 256 in Hb), GEMM -> h2
  k_agg<<<(NN + 3) / 4, 256, 0, stream>>>(Hb, 256, psrc, rp2, A2);
  k_gemm<<<mgrid, 256, 0, stream>>>(A2, KA, WT + (size_t)DD * KA, KA, NN, KA, bias + DD,
                                    out + (size_t)2 * NN * DD, Hb, DD, 1);

  // projection: final = [h1|h2] @ proj_w + proj_b (no relu)
  k_gemm<<<mgrid, 256, 0, stream>>>(Hb, 256, PT, 256, NN, 256, proj_b,
                                    out, (unsigned short*)nullptr, 0, 0);
}